// Round 8
// baseline (967.401 us; speedup 1.0000x reference)
//
#include <hip/hip_runtime.h>
#include <hip/hip_bf16.h>
#include <math.h>

#define NP   19000      // NUM_PROTEINS (= 4*4750)
#define ND   1024       // NUM_DRUGS
#define CHN  256        // IN_CH == EMBED
#define ESG  1500000    // E_SG
#define NSG  800000     // N_SG
#define BDD  4096       // B_DD

#define GEMM_BX   ((NP + 63) / 64)       // 297
#define GEMM_BLK  (GEMM_BX * 4)          // 1188
#define FILL_BLK  ((ESG + 255) / 256)    // 5860

// ---------------------------------------------------------------- bf16 helpers (raw ushort)
static __device__ __forceinline__ unsigned short f2bf(float f) {
    unsigned u = __float_as_uint(f);
    u = u + 0x7fffu + ((u >> 16) & 1u);        // round-to-nearest-even
    return (unsigned short)(u >> 16);
}
static __device__ __forceinline__ float bf2f(unsigned short h) {
    return __uint_as_float((unsigned)h << 16);
}

// ---------------------------------------------------------------- utilities
static __device__ __forceinline__ int lower_bound_dev(const int* __restrict__ arr, int n, int val) {
    int lo = 0, hi = n;
    while (lo < hi) {
        int mid = (lo + hi) >> 1;
        if (arr[mid] < val) lo = mid + 1; else hi = mid;
    }
    return lo;
}

// ---------------------------------------------------------------- degree
__global__ void deg_kernel(const int* __restrict__ dst, int* __restrict__ deg) {
    int e = blockIdx.x * blockDim.x + threadIdx.x;
    if (e < ESG) atomicAdd(&deg[dst[e]], 1);
}

// single-block exclusive scan of degree -> row_ptr; seeds cursor; computes dinv
__global__ void scan_kernel(const int* __restrict__ deg, int* __restrict__ row_ptr,
                            int* __restrict__ cursor, float* __restrict__ dinv) {
    const int T = 256;
    const int PER = (NP + T - 1) / T;   // 75
    __shared__ int totals[T];
    __shared__ int excl[T + 1];
    int t = threadIdx.x;
    int base = t * PER;
    int local = 0;
    for (int i = 0; i < PER; i++) {
        int idx = base + i;
        if (idx < NP) local += deg[idx];
    }
    totals[t] = local;
    __syncthreads();
    if (t == 0) {
        int r = 0;
        for (int i = 0; i < T; i++) { excl[i] = r; r += totals[i]; }
        excl[T] = r;
    }
    __syncthreads();
    int run = excl[t];
    for (int i = 0; i < PER; i++) {
        int idx = base + i;
        if (idx < NP) {
            int dg = deg[idx];
            row_ptr[idx] = run;
            cursor[idx]  = run;
            dinv[idx]    = 1.0f / sqrtf((float)dg + 1.0f);
            run += dg;
        }
    }
    if (t == 0) row_ptr[NP] = excl[T];
}

// ---------------------------------------------------------------- GEMM body
// C[M,256] = A[M,256] @ B[256,256]; 64x64 tile, 4x4/thread; dual fp32+bf16 out.
static __device__ __forceinline__ void gemm_body(const float* __restrict__ A,
                                                 const float* __restrict__ B,
                                                 float* __restrict__ C,
                                                 unsigned short* __restrict__ Cb,
                                                 int M, int bx, int by) {
    __shared__ float As[16][68];   // transposed: As[k][m]
    __shared__ float Bs[16][68];   // Bs[k][n]
    int tid = threadIdx.x;
    int m0 = bx * 64;
    int n0 = by * 64;
    int tx = tid & 15;
    int ty = tid >> 4;
    int ar = tid >> 2;
    int ak = (tid & 3) << 2;
    int bk = tid >> 4;
    int bn = (tid & 15) << 2;
    float acc[4][4] = {};
    for (int k0 = 0; k0 < 256; k0 += 16) {
        float4 av = make_float4(0.f, 0.f, 0.f, 0.f);
        int arow = m0 + ar;
        if (arow < M) av = *(const float4*)(A + (size_t)arow * 256 + k0 + ak);
        As[ak + 0][ar] = av.x; As[ak + 1][ar] = av.y;
        As[ak + 2][ar] = av.z; As[ak + 3][ar] = av.w;
        float4 bv = *(const float4*)(B + (size_t)(k0 + bk) * 256 + n0 + bn);
        *(float4*)&Bs[bk][bn] = bv;
        __syncthreads();
#pragma unroll
        for (int kk = 0; kk < 16; kk++) {
            float4 a = *(const float4*)&As[kk][ty << 2];
            float4 b = *(const float4*)&Bs[kk][tx << 2];
            acc[0][0] += a.x * b.x; acc[0][1] += a.x * b.y; acc[0][2] += a.x * b.z; acc[0][3] += a.x * b.w;
            acc[1][0] += a.y * b.x; acc[1][1] += a.y * b.y; acc[1][2] += a.y * b.z; acc[1][3] += a.y * b.w;
            acc[2][0] += a.z * b.x; acc[2][1] += a.z * b.y; acc[2][2] += a.z * b.z; acc[2][3] += a.z * b.w;
            acc[3][0] += a.w * b.x; acc[3][1] += a.w * b.y; acc[3][2] += a.w * b.z; acc[3][3] += a.w * b.w;
        }
        __syncthreads();
    }
#pragma unroll
    for (int i = 0; i < 4; i++) {
        int row = m0 + (ty << 2) + i;
        if (row < M) {
            size_t o = (size_t)row * 256 + n0 + (tx << 2);
            float4 v = make_float4(acc[i][0], acc[i][1], acc[i][2], acc[i][3]);
            *(float4*)(C + o) = v;
            ushort4 vb;
            vb.x = f2bf(v.x); vb.y = f2bf(v.y); vb.z = f2bf(v.z); vb.w = f2bf(v.w);
            *(ushort4*)(Cb + o) = vb;
        }
    }
}

// ---------------------------------------------------------------- plain gemm kernel (layer 2)
__global__ __launch_bounds__(256) void gemm_kernel(const float* __restrict__ A,
                                                   const float* __restrict__ B,
                                                   float* __restrict__ C,
                                                   unsigned short* __restrict__ Cb,
                                                   int M) {
    gemm_body(A, B, C, Cb, M, blockIdx.x, blockIdx.y);
}

// ---------------------------------------------------------------- fused fill + gemm1
// gemm blocks first (compute-bound), fill blocks after (write/latency-bound).
// CSR record = ushort src only (2 B scattered store); weights recomputed from
// dinv at use-time, bit-identical to dinv[s]*dinv[d].
__global__ __launch_bounds__(256) void fill_gemm_kernel(const int* __restrict__ src,
                                                        const int* __restrict__ dst,
                                                        int* __restrict__ cursor,
                                                        unsigned short* __restrict__ csr_srcu,
                                                        const float* __restrict__ A,
                                                        const float* __restrict__ B,
                                                        float* __restrict__ C,
                                                        unsigned short* __restrict__ Cb) {
    if (blockIdx.x < GEMM_BLK) {
        gemm_body(A, B, C, Cb, NP, blockIdx.x >> 2, blockIdx.x & 3);
        return;
    }
    int e = (blockIdx.x - GEMM_BLK) * 256 + threadIdx.x;
    if (e >= ESG) return;
    int s = src[e], d = dst[e];
    int pos = atomicAdd(&cursor[d], 1);
    csr_srcu[pos] = (unsigned short)s;
}

// ---------------------------------------------------------------- SpMM, XCD-sliced
// grid = NP blocks of 256 (4 waves): block = 4 rows x ONE 64-ch slice.
// slice = blockIdx&3, row-quad = blockIdx>>2 (0..NP/4). Blocks round-robin
// XCDs by blockIdx%8 -> XCD k only touches slice k%4: per-XCD gather set
// = 19000 x 64ch x 2B = 2.43 MB, L2-resident.
// Wave = one row x one slice; lane loads 2B; src wave-uniform -> scalar.
__global__ __launch_bounds__(256) void spmm_kernel(const unsigned short* __restrict__ hwbf,
                                                   const float* __restrict__ hw,
                                                   const int* __restrict__ row_ptr,
                                                   const unsigned short* __restrict__ csr_srcu,
                                                   const float* __restrict__ dinv,
                                                   const float* __restrict__ bias,
                                                   const float* __restrict__ residual,
                                                   float* __restrict__ outf,
                                                   unsigned short* __restrict__ outbf,
                                                   int do_relu) {
    int b     = blockIdx.x;
    int slice = b & 3;
    int quad  = b >> 2;                        // 0 .. NP/4-1
    int wv    = threadIdx.x >> 6;
    int lane  = threadIdx.x & 63;
    int row   = quad * 4 + wv;                 // < NP
    int c     = slice * 64 + lane;
    int lo = __builtin_amdgcn_readfirstlane(row_ptr[row]);
    int hi = __builtin_amdgcn_readfirstlane(row_ptr[row + 1]);
    float dvr = dinv[row];
    float acc = 0.f;
    const unsigned short* hp = hwbf + c;
#pragma unroll 4
    for (int e = lo; e < hi; e++) {
        int s = __builtin_amdgcn_readfirstlane((int)csr_srcu[e]);  // uniform
        float w = dvr * dinv[s];                                   // scalar table lookup
        acc += w * bf2f(hp[(size_t)s * 256]);
    }
    size_t o = (size_t)row * 256 + c;
    acc += hw[o] * (dvr * dvr) + bias[c];
    if (residual) acc += residual[o];
    if (do_relu) acc = fmaxf(acc, 0.f);
    if (outf)  outf[o] = acc;
    if (outbf) outbf[o] = f2bf(acc);
}

// ---------------------------------------------------------------- pooling, XCD-sliced
// grid = ND*4 blocks; slice = blockIdx&3, drug = blockIdx>>2. 4 waves split the
// drug's node list into quarters over the same 64-ch slice; block reduce.
__global__ __launch_bounds__(256) void pool_kernel(const unsigned short* __restrict__ h2bf,
                                                   const int* __restrict__ sg_nodes,
                                                   const int* __restrict__ sg_idx,
                                                   float* __restrict__ drug_emb) {
    int b     = blockIdx.x;
    int slice = b & 3;
    int d     = b >> 2;                        // < ND
    int wv    = threadIdx.x >> 6;
    int lane  = threadIdx.x & 63;
    int c     = slice * 64 + lane;
    __shared__ float s_red[4][64];
    int lo0 = lower_bound_dev(sg_idx, NSG, d);       // uniform across block
    int hi0 = lower_bound_dev(sg_idx, NSG, d + 1);
    int len = hi0 - lo0;
    int lo = __builtin_amdgcn_readfirstlane(lo0 + (int)(((long long)len * wv) / 4));
    int hi = __builtin_amdgcn_readfirstlane(lo0 + (int)(((long long)len * (wv + 1)) / 4));
    float acc = 0.f;
    const unsigned short* hp = h2bf + c;
#pragma unroll 4
    for (int e = lo; e < hi; e++) {
        int s = __builtin_amdgcn_readfirstlane(sg_nodes[e]);   // uniform address
        acc += bf2f(hp[(size_t)s * 256]);
    }
    s_red[wv][lane] = acc;
    __syncthreads();
    if (wv == 0) {
        float inv = 1.0f / (float)max(len, 1);
        float r = (s_red[0][lane] + s_red[1][lane]) + (s_red[2][lane] + s_red[3][lane]);
        drug_emb[(size_t)d * 256 + c] = r * inv;
    }
}

// ---------------------------------------------------------------- dot head (wave per pair)
__global__ __launch_bounds__(256) void dot_kernel(const float* __restrict__ drug_emb,
                                                  const int* __restrict__ ddb,
                                                  float* __restrict__ out) {
    int wave = threadIdx.x >> 6;
    int lane = threadIdx.x & 63;
    int p = blockIdx.x * 4 + wave;
    if (p >= BDD) return;
    int a = ddb[p];
    int b = ddb[BDD + p];
    const float4* ea = (const float4*)(drug_emb + (size_t)a * 256);
    const float4* eb = (const float4*)(drug_emb + (size_t)b * 256);
    float4 va = ea[lane];
    float4 vb = eb[lane];
    float s = va.x * vb.x + va.y * vb.y + va.z * vb.z + va.w * vb.w;
#pragma unroll
    for (int off = 32; off > 0; off >>= 1) s += __shfl_down(s, off, 64);
    if (lane == 0) out[p] = s;
}

// ---------------------------------------------------------------- launcher
extern "C" void kernel_launch(void* const* d_in, const int* in_sizes, int n_in,
                              void* d_out, int out_size, void* d_ws, size_t ws_size,
                              hipStream_t stream) {
    const float* x        = (const float*)d_in[0];
    const int*   ddb      = (const int*)d_in[1];
    // d_in[2] edge_attr, d_in[3] edge_cell_lines: unused by reference
    const int*   sg_edge  = (const int*)d_in[4];   // [2, ESG]: src then dst
    const int*   sg_nodes = (const int*)d_in[5];
    const int*   sg_idx   = (const int*)d_in[6];
    const float* W1       = (const float*)d_in[7];
    const float* b1       = (const float*)d_in[8];
    const float* W2       = (const float*)d_in[9];
    const float* b2       = (const float*)d_in[10];
    float* out = (float*)d_out;

    char* ws = (char*)d_ws;
    size_t off = 0;
    auto alloc = [&](size_t bytes) -> void* {
        void* p = ws + off;
        off = (off + bytes + 255) & ~(size_t)255;
        return p;
    };
    int*   deg      = (int*)alloc(NP * sizeof(int));
    float* dinv     = (float*)alloc(NP * sizeof(float));
    int*   row_ptr  = (int*)alloc((NP + 1) * sizeof(int));
    int*   cursor   = (int*)alloc(NP * sizeof(int));
    unsigned short* csr_srcu = (unsigned short*)alloc((size_t)ESG * sizeof(unsigned short));
    float* bufA     = (float*)alloc((size_t)NP * CHN * sizeof(float));            // hw1, then hw2
    unsigned short* bufAbf = (unsigned short*)alloc((size_t)NP * CHN * 2);        // bf16 twin
    float* h1       = (float*)alloc((size_t)NP * CHN * sizeof(float));
    unsigned short* h2bf   = (unsigned short*)alloc((size_t)NP * CHN * 2);
    float* drug_emb = (float*)alloc((size_t)ND * CHN * sizeof(float));

    const int* src = sg_edge;
    const int* dst = sg_edge + ESG;

    hipMemsetAsync(deg, 0, NP * sizeof(int), stream);
    deg_kernel<<<(ESG + 255) / 256, 256, 0, stream>>>(dst, deg);
    scan_kernel<<<1, 256, 0, stream>>>(deg, row_ptr, cursor, dinv);

    // fused: CSR fill (ushort src) + gemm1 (bufA/bufAbf = x @ W1)
    fill_gemm_kernel<<<GEMM_BLK + FILL_BLK, 256, 0, stream>>>(src, dst, cursor,
                                                              csr_srcu, x, W1, bufA, bufAbf);
    // layer 1: h1 = relu(agg(bf16 sliced gather) + self + b1)   [fp32 out only]
    spmm_kernel<<<NP, 256, 0, stream>>>(bufAbf, bufA, row_ptr, csr_srcu, dinv, b1,
                                        nullptr, h1, nullptr, 1);
    // layer 2: bufA/bufAbf = h1 @ W2 ; h2bf = agg + self + b2 + h1  [bf16 out only]
    gemm_kernel<<<dim3(GEMM_BX, 4), 256, 0, stream>>>(h1, W2, bufA, bufAbf, NP);
    spmm_kernel<<<NP, 256, 0, stream>>>(bufAbf, bufA, row_ptr, csr_srcu, dinv, b2,
                                        h1, nullptr, h2bf, 0);
    // scatter-mean pooling (XCD-sliced, wave-split, block reduce)
    pool_kernel<<<ND * 4, 256, 0, stream>>>(h2bf, sg_nodes, sg_idx, drug_emb);
    // dot-product head
    dot_kernel<<<(BDD + 3) / 4, 256, 0, stream>>>(drug_emb, ddb, out);
}

// Round 9
// 651.619 us; speedup vs baseline: 1.4846x; 1.4846x over previous
//
#include <hip/hip_runtime.h>
#include <hip/hip_bf16.h>
#include <math.h>

#define NP   19000      // NUM_PROTEINS (= 4*4750)
#define ND   1024       // NUM_DRUGS
#define CHN  256        // IN_CH == EMBED
#define ESG  1500000    // E_SG
#define NSG  800000     // N_SG
#define BDD  4096       // B_DD

#define GEMM_BX   ((NP + 63) / 64)       // 297
#define GEMM_BLK  (GEMM_BX * 4)          // 1188
#define FILL_BLK  ((ESG + 255) / 256)    // 5860

// ---------------------------------------------------------------- bf16 helpers (raw ushort)
static __device__ __forceinline__ unsigned short f2bf(float f) {
    unsigned u = __float_as_uint(f);
    u = u + 0x7fffu + ((u >> 16) & 1u);        // round-to-nearest-even
    return (unsigned short)(u >> 16);
}
static __device__ __forceinline__ float bf2f(unsigned short h) {
    return __uint_as_float((unsigned)h << 16);
}

// ---------------------------------------------------------------- utilities
static __device__ __forceinline__ int lower_bound_dev(const int* __restrict__ arr, int n, int val) {
    int lo = 0, hi = n;
    while (lo < hi) {
        int mid = (lo + hi) >> 1;
        if (arr[mid] < val) lo = mid + 1; else hi = mid;
    }
    return lo;
}

// ---------------------------------------------------------------- degree
__global__ void deg_kernel(const int* __restrict__ dst, int* __restrict__ deg) {
    int e = blockIdx.x * blockDim.x + threadIdx.x;
    if (e < ESG) atomicAdd(&deg[dst[e]], 1);
}

// single-block exclusive scan of degree -> row_ptr; seeds cursor; computes dinv
__global__ void scan_kernel(const int* __restrict__ deg, int* __restrict__ row_ptr,
                            int* __restrict__ cursor, float* __restrict__ dinv) {
    const int T = 256;
    const int PER = (NP + T - 1) / T;   // 75
    __shared__ int totals[T];
    __shared__ int excl[T + 1];
    int t = threadIdx.x;
    int base = t * PER;
    int local = 0;
    for (int i = 0; i < PER; i++) {
        int idx = base + i;
        if (idx < NP) local += deg[idx];
    }
    totals[t] = local;
    __syncthreads();
    if (t == 0) {
        int r = 0;
        for (int i = 0; i < T; i++) { excl[i] = r; r += totals[i]; }
        excl[T] = r;
    }
    __syncthreads();
    int run = excl[t];
    for (int i = 0; i < PER; i++) {
        int idx = base + i;
        if (idx < NP) {
            int dg = deg[idx];
            row_ptr[idx] = run;
            cursor[idx]  = run;
            dinv[idx]    = 1.0f / sqrtf((float)dg + 1.0f);
            run += dg;
        }
    }
    if (t == 0) row_ptr[NP] = excl[T];
}

// ---------------------------------------------------------------- GEMM body
// C[M,256] = A[M,256] @ B[256,256]; 64x64 tile, 4x4/thread.
// fp32 out unscaled; bf16 twin PRESCALED by dinv[row] (so SpMM's edge weight
// dinv[s]*dinv[d] becomes gather + one multiply by dinv[row] at the end).
static __device__ __forceinline__ void gemm_body(const float* __restrict__ A,
                                                 const float* __restrict__ B,
                                                 const float* __restrict__ dinv,
                                                 float* __restrict__ C,
                                                 unsigned short* __restrict__ Cb,
                                                 int M, int bx, int by) {
    __shared__ float As[16][68];   // transposed: As[k][m]
    __shared__ float Bs[16][68];   // Bs[k][n]
    int tid = threadIdx.x;
    int m0 = bx * 64;
    int n0 = by * 64;
    int tx = tid & 15;
    int ty = tid >> 4;
    int ar = tid >> 2;
    int ak = (tid & 3) << 2;
    int bk = tid >> 4;
    int bn = (tid & 15) << 2;
    float acc[4][4] = {};
    for (int k0 = 0; k0 < 256; k0 += 16) {
        float4 av = make_float4(0.f, 0.f, 0.f, 0.f);
        int arow = m0 + ar;
        if (arow < M) av = *(const float4*)(A + (size_t)arow * 256 + k0 + ak);
        As[ak + 0][ar] = av.x; As[ak + 1][ar] = av.y;
        As[ak + 2][ar] = av.z; As[ak + 3][ar] = av.w;
        float4 bv = *(const float4*)(B + (size_t)(k0 + bk) * 256 + n0 + bn);
        *(float4*)&Bs[bk][bn] = bv;
        __syncthreads();
#pragma unroll
        for (int kk = 0; kk < 16; kk++) {
            float4 a = *(const float4*)&As[kk][ty << 2];
            float4 b = *(const float4*)&Bs[kk][tx << 2];
            acc[0][0] += a.x * b.x; acc[0][1] += a.x * b.y; acc[0][2] += a.x * b.z; acc[0][3] += a.x * b.w;
            acc[1][0] += a.y * b.x; acc[1][1] += a.y * b.y; acc[1][2] += a.y * b.z; acc[1][3] += a.y * b.w;
            acc[2][0] += a.z * b.x; acc[2][1] += a.z * b.y; acc[2][2] += a.z * b.z; acc[2][3] += a.z * b.w;
            acc[3][0] += a.w * b.x; acc[3][1] += a.w * b.y; acc[3][2] += a.w * b.z; acc[3][3] += a.w * b.w;
        }
        __syncthreads();
    }
#pragma unroll
    for (int i = 0; i < 4; i++) {
        int row = m0 + (ty << 2) + i;
        if (row < M) {
            size_t o = (size_t)row * 256 + n0 + (tx << 2);
            float4 v = make_float4(acc[i][0], acc[i][1], acc[i][2], acc[i][3]);
            *(float4*)(C + o) = v;
            float dv = dinv[row];
            ushort4 vb;
            vb.x = f2bf(v.x * dv); vb.y = f2bf(v.y * dv);
            vb.z = f2bf(v.z * dv); vb.w = f2bf(v.w * dv);
            *(ushort4*)(Cb + o) = vb;
        }
    }
}

// ---------------------------------------------------------------- plain gemm kernel (layer 2)
__global__ __launch_bounds__(256) void gemm_kernel(const float* __restrict__ A,
                                                   const float* __restrict__ B,
                                                   const float* __restrict__ dinv,
                                                   float* __restrict__ C,
                                                   unsigned short* __restrict__ Cb,
                                                   int M) {
    gemm_body(A, B, dinv, C, Cb, M, blockIdx.x, blockIdx.y);
}

// ---------------------------------------------------------------- fused fill + gemm1
// gemm blocks first (compute-bound), fill blocks after (write/latency-bound).
// CSR record = ushort src only (2 B scattered store).
__global__ __launch_bounds__(256) void fill_gemm_kernel(const int* __restrict__ src,
                                                        const int* __restrict__ dst,
                                                        int* __restrict__ cursor,
                                                        unsigned short* __restrict__ csr_srcu,
                                                        const float* __restrict__ A,
                                                        const float* __restrict__ B,
                                                        const float* __restrict__ dinv,
                                                        float* __restrict__ C,
                                                        unsigned short* __restrict__ Cb) {
    if (blockIdx.x < GEMM_BLK) {
        gemm_body(A, B, dinv, C, Cb, NP, blockIdx.x >> 2, blockIdx.x & 3);
        return;
    }
    int e = (blockIdx.x - GEMM_BLK) * 256 + threadIdx.x;
    if (e >= ESG) return;
    int s = src[e], d = dst[e];
    int pos = atomicAdd(&cursor[d], 1);
    csr_srcu[pos] = (unsigned short)s;
}

// ---------------------------------------------------------------- SpMM, XCD-sliced + 4-edge packed
// grid = NP blocks (4 waves): block = 4 rows x ONE 64-ch slice (slice=blockIdx&3,
// quad=blockIdx>>2). Blocks round-robin XCDs by blockIdx%8 -> XCD k touches only
// slice k%4: 19000x64x2B = 2.43 MB per-XCD gather set, L2-resident.
// Wave packing: 4 edge-groups x 16 lanes; lane = ushort4 (4 ch, 8 B) -> one
// 512 B gather per 4 edges. Gathered matrix is PRESCALED by dinv[src]; the
// row factor dinv[row] is applied once after the cross-group reduce.
__global__ __launch_bounds__(256) void spmm_kernel(const unsigned short* __restrict__ hwbf,
                                                   const float* __restrict__ hw,
                                                   const int* __restrict__ row_ptr,
                                                   const unsigned short* __restrict__ csr_srcu,
                                                   const float* __restrict__ dinv,
                                                   const float* __restrict__ bias,
                                                   const float* __restrict__ residual,
                                                   float* __restrict__ outf,
                                                   unsigned short* __restrict__ outbf,
                                                   int do_relu) {
    int b     = blockIdx.x;
    int slice = b & 3;
    int quad  = b >> 2;                        // 0 .. NP/4-1
    int wv    = threadIdx.x >> 6;
    int lane  = threadIdx.x & 63;
    int g     = lane >> 4;                     // edge group 0..3
    int l     = lane & 15;                     // channel quad within slice
    int row   = quad * 4 + wv;                 // < NP
    int c     = slice * 64 + (l << 2);
    int lo = __builtin_amdgcn_readfirstlane(row_ptr[row]);
    int hi = __builtin_amdgcn_readfirstlane(row_ptr[row + 1]);
    float a0 = 0.f, a1 = 0.f, a2 = 0.f, a3 = 0.f;
    const unsigned short* hp = hwbf + c;
    for (int base = lo; base < hi; base += 4) {
        int e = base + g;
        bool valid = e < hi;
        int s = csr_srcu[valid ? e : lo];      // group-uniform 2B load, safe index
        ushort4 hv = *(const ushort4*)(hp + (size_t)s * 256);
        if (valid) {
            a0 += bf2f(hv.x); a1 += bf2f(hv.y);
            a2 += bf2f(hv.z); a3 += bf2f(hv.w);
        }
    }
    // combine the 4 edge-groups (same channels, different edges)
    a0 += __shfl_xor(a0, 16); a1 += __shfl_xor(a1, 16);
    a2 += __shfl_xor(a2, 16); a3 += __shfl_xor(a3, 16);
    a0 += __shfl_xor(a0, 32); a1 += __shfl_xor(a1, 32);
    a2 += __shfl_xor(a2, 32); a3 += __shfl_xor(a3, 32);
    if (g == 0) {
        float dvr = dinv[row];
        float sn  = dvr * dvr;
        size_t o = (size_t)row * 256 + c;
        float4 hv = *(const float4*)(hw + o);
        float4 bv = *(const float4*)(bias + c);
        a0 = a0 * dvr + hv.x * sn + bv.x;
        a1 = a1 * dvr + hv.y * sn + bv.y;
        a2 = a2 * dvr + hv.z * sn + bv.z;
        a3 = a3 * dvr + hv.w * sn + bv.w;
        if (residual) {
            float4 rv = *(const float4*)(residual + o);
            a0 += rv.x; a1 += rv.y; a2 += rv.z; a3 += rv.w;
        }
        if (do_relu) {
            a0 = fmaxf(a0, 0.f); a1 = fmaxf(a1, 0.f);
            a2 = fmaxf(a2, 0.f); a3 = fmaxf(a3, 0.f);
        }
        if (outf)  *(float4*)(outf + o) = make_float4(a0, a1, a2, a3);
        if (outbf) {
            ushort4 ob; ob.x = f2bf(a0); ob.y = f2bf(a1); ob.z = f2bf(a2); ob.w = f2bf(a3);
            *(ushort4*)(outbf + o) = ob;
        }
    }
}

// ---------------------------------------------------------------- pooling, XCD-sliced + 4-node packed
// grid = ND*4; slice = blockIdx&3, drug = blockIdx>>2. 4 waves = 4 quarters of
// the node list; within a wave: 4 node-groups x 16 lanes x ushort4.
__global__ __launch_bounds__(256) void pool_kernel(const unsigned short* __restrict__ h2bf,
                                                   const int* __restrict__ sg_nodes,
                                                   const int* __restrict__ sg_idx,
                                                   float* __restrict__ drug_emb) {
    int b     = blockIdx.x;
    int slice = b & 3;
    int d     = b >> 2;                        // < ND
    int wv    = threadIdx.x >> 6;
    int lane  = threadIdx.x & 63;
    int g     = lane >> 4;
    int l     = lane & 15;
    int c     = slice * 64 + (l << 2);
    __shared__ float s_red[4][64];
    int lo0 = lower_bound_dev(sg_idx, NSG, d);       // uniform across block
    int hi0 = lower_bound_dev(sg_idx, NSG, d + 1);
    int len = hi0 - lo0;
    int lo = __builtin_amdgcn_readfirstlane(lo0 + (int)(((long long)len * wv) / 4));
    int hi = __builtin_amdgcn_readfirstlane(lo0 + (int)(((long long)len * (wv + 1)) / 4));
    float a0 = 0.f, a1 = 0.f, a2 = 0.f, a3 = 0.f;
    const unsigned short* hp = h2bf + c;
    for (int base = lo; base < hi; base += 4) {
        int e = base + g;
        bool valid = e < hi;
        int s = sg_nodes[valid ? e : lo];
        ushort4 hv = *(const ushort4*)(hp + (size_t)s * 256);
        if (valid) {
            a0 += bf2f(hv.x); a1 += bf2f(hv.y);
            a2 += bf2f(hv.z); a3 += bf2f(hv.w);
        }
    }
    a0 += __shfl_xor(a0, 16); a1 += __shfl_xor(a1, 16);
    a2 += __shfl_xor(a2, 16); a3 += __shfl_xor(a3, 16);
    a0 += __shfl_xor(a0, 32); a1 += __shfl_xor(a1, 32);
    a2 += __shfl_xor(a2, 32); a3 += __shfl_xor(a3, 32);
    if (g == 0) *(float4*)&s_red[wv][l << 2] = make_float4(a0, a1, a2, a3);
    __syncthreads();
    if (threadIdx.x < 64) {
        int t = threadIdx.x;
        float inv = 1.0f / (float)max(len, 1);
        float r = (s_red[0][t] + s_red[1][t]) + (s_red[2][t] + s_red[3][t]);
        drug_emb[(size_t)d * 256 + slice * 64 + t] = r * inv;
    }
}

// ---------------------------------------------------------------- dot head (wave per pair)
__global__ __launch_bounds__(256) void dot_kernel(const float* __restrict__ drug_emb,
                                                  const int* __restrict__ ddb,
                                                  float* __restrict__ out) {
    int wave = threadIdx.x >> 6;
    int lane = threadIdx.x & 63;
    int p = blockIdx.x * 4 + wave;
    if (p >= BDD) return;
    int a = ddb[p];
    int b = ddb[BDD + p];
    const float4* ea = (const float4*)(drug_emb + (size_t)a * 256);
    const float4* eb = (const float4*)(drug_emb + (size_t)b * 256);
    float4 va = ea[lane];
    float4 vb = eb[lane];
    float s = va.x * vb.x + va.y * vb.y + va.z * vb.z + va.w * vb.w;
#pragma unroll
    for (int off = 32; off > 0; off >>= 1) s += __shfl_down(s, off, 64);
    if (lane == 0) out[p] = s;
}

// ---------------------------------------------------------------- launcher
extern "C" void kernel_launch(void* const* d_in, const int* in_sizes, int n_in,
                              void* d_out, int out_size, void* d_ws, size_t ws_size,
                              hipStream_t stream) {
    const float* x        = (const float*)d_in[0];
    const int*   ddb      = (const int*)d_in[1];
    // d_in[2] edge_attr, d_in[3] edge_cell_lines: unused by reference
    const int*   sg_edge  = (const int*)d_in[4];   // [2, ESG]: src then dst
    const int*   sg_nodes = (const int*)d_in[5];
    const int*   sg_idx   = (const int*)d_in[6];
    const float* W1       = (const float*)d_in[7];
    const float* b1       = (const float*)d_in[8];
    const float* W2       = (const float*)d_in[9];
    const float* b2       = (const float*)d_in[10];
    float* out = (float*)d_out;

    char* ws = (char*)d_ws;
    size_t off = 0;
    auto alloc = [&](size_t bytes) -> void* {
        void* p = ws + off;
        off = (off + bytes + 255) & ~(size_t)255;
        return p;
    };
    int*   deg      = (int*)alloc(NP * sizeof(int));
    float* dinv     = (float*)alloc(NP * sizeof(float));
    int*   row_ptr  = (int*)alloc((NP + 1) * sizeof(int));
    int*   cursor   = (int*)alloc(NP * sizeof(int));
    unsigned short* csr_srcu = (unsigned short*)alloc((size_t)ESG * sizeof(unsigned short));
    float* bufA     = (float*)alloc((size_t)NP * CHN * sizeof(float));            // hw1, then hw2
    unsigned short* bufAbf = (unsigned short*)alloc((size_t)NP * CHN * 2);        // bf16 twin (prescaled)
    float* h1       = (float*)alloc((size_t)NP * CHN * sizeof(float));
    unsigned short* h2bf   = (unsigned short*)alloc((size_t)NP * CHN * 2);
    float* drug_emb = (float*)alloc((size_t)ND * CHN * sizeof(float));

    const int* src = sg_edge;
    const int* dst = sg_edge + ESG;

    hipMemsetAsync(deg, 0, NP * sizeof(int), stream);
    deg_kernel<<<(ESG + 255) / 256, 256, 0, stream>>>(dst, deg);
    scan_kernel<<<1, 256, 0, stream>>>(deg, row_ptr, cursor, dinv);

    // fused: CSR fill (ushort src) + gemm1 (bufA fp32; bufAbf bf16 prescaled)
    fill_gemm_kernel<<<GEMM_BLK + FILL_BLK, 256, 0, stream>>>(src, dst, cursor,
                                                              csr_srcu, x, W1, dinv,
                                                              bufA, bufAbf);
    // layer 1: h1 = relu(agg(sliced gather) + self + b1)   [fp32 out only]
    spmm_kernel<<<NP, 256, 0, stream>>>(bufAbf, bufA, row_ptr, csr_srcu, dinv, b1,
                                        nullptr, h1, nullptr, 1);
    // layer 2: bufA/bufAbf = h1 @ W2 ; h2bf = agg + self + b2 + h1  [bf16 out only]
    gemm_kernel<<<dim3(GEMM_BX, 4), 256, 0, stream>>>(h1, W2, dinv, bufA, bufAbf, NP);
    spmm_kernel<<<NP, 256, 0, stream>>>(bufAbf, bufA, row_ptr, csr_srcu, dinv, b2,
                                        h1, nullptr, h2bf, 0);
    // scatter-mean pooling (XCD-sliced, 4-node packed)
    pool_kernel<<<ND * 4, 256, 0, stream>>>(h2bf, sg_nodes, sg_idx, drug_emb);
    // dot-product head
    dot_kernel<<<(BDD + 3) / 4, 256, 0, stream>>>(drug_emb, ddb, out);
}

// Round 11
// 541.399 us; speedup vs baseline: 1.7869x; 1.2036x over previous
//
#include <hip/hip_runtime.h>
#include <hip/hip_bf16.h>
#include <math.h>

#define NP   19000      // NUM_PROTEINS (= 4*4750)
#define ND   1024       // NUM_DRUGS
#define CHN  256        // IN_CH == EMBED
#define ESG  1500000    // E_SG
#define NSG  800000     // N_SG
#define BDD  4096       // B_DD

#define GEMM_BX   ((NP + 63) / 64)       // 297
#define GEMM_BLK  (GEMM_BX * 4)          // 1188
#define FILL_BLK  ((ESG + 255) / 256)    // 5860

// ---------------------------------------------------------------- bf16 helpers (raw ushort)
static __device__ __forceinline__ unsigned short f2bf(float f) {
    unsigned u = __float_as_uint(f);
    u = u + 0x7fffu + ((u >> 16) & 1u);        // round-to-nearest-even
    return (unsigned short)(u >> 16);
}
static __device__ __forceinline__ float bf2f(unsigned short h) {
    return __uint_as_float((unsigned)h << 16);
}

// ---------------------------------------------------------------- utilities
static __device__ __forceinline__ int lower_bound_dev(const int* __restrict__ arr, int n, int val) {
    int lo = 0, hi = n;
    while (lo < hi) {
        int mid = (lo + hi) >> 1;
        if (arr[mid] < val) lo = mid + 1; else hi = mid;
    }
    return lo;
}

// ---------------------------------------------------------------- degree
__global__ void deg_kernel(const int* __restrict__ dst, int* __restrict__ deg) {
    int e = blockIdx.x * blockDim.x + threadIdx.x;
    if (e < ESG) atomicAdd(&deg[dst[e]], 1);
}

// single-block exclusive scan of degree -> row_ptr; seeds cursor; computes dinv
__global__ void scan_kernel(const int* __restrict__ deg, int* __restrict__ row_ptr,
                            int* __restrict__ cursor, float* __restrict__ dinv) {
    const int T = 256;
    const int PER = (NP + T - 1) / T;   // 75
    __shared__ int totals[T];
    __shared__ int excl[T + 1];
    int t = threadIdx.x;
    int base = t * PER;
    int local = 0;
    for (int i = 0; i < PER; i++) {
        int idx = base + i;
        if (idx < NP) local += deg[idx];
    }
    totals[t] = local;
    __syncthreads();
    if (t == 0) {
        int r = 0;
        for (int i = 0; i < T; i++) { excl[i] = r; r += totals[i]; }
        excl[T] = r;
    }
    __syncthreads();
    int run = excl[t];
    for (int i = 0; i < PER; i++) {
        int idx = base + i;
        if (idx < NP) {
            int dg = deg[idx];
            row_ptr[idx] = run;
            cursor[idx]  = run;
            dinv[idx]    = 1.0f / sqrtf((float)dg + 1.0f);
            run += dg;
        }
    }
    if (t == 0) row_ptr[NP] = excl[T];
}

// ---------------------------------------------------------------- GEMM body
// C[M,256] = A[M,256] @ B[256,256]; 64x64 tile, 4x4/thread.
// fp32 out unscaled; bf16 twin PRESCALED by dinv[row].
static __device__ __forceinline__ void gemm_body(const float* __restrict__ A,
                                                 const float* __restrict__ B,
                                                 const float* __restrict__ dinv,
                                                 float* __restrict__ C,
                                                 unsigned short* __restrict__ Cb,
                                                 int M, int bx, int by) {
    __shared__ float As[16][68];   // transposed: As[k][m]
    __shared__ float Bs[16][68];   // Bs[k][n]
    int tid = threadIdx.x;
    int m0 = bx * 64;
    int n0 = by * 64;
    int tx = tid & 15;
    int ty = tid >> 4;
    int ar = tid >> 2;
    int ak = (tid & 3) << 2;
    int bk = tid >> 4;
    int bn = (tid & 15) << 2;
    float acc[4][4] = {};
    for (int k0 = 0; k0 < 256; k0 += 16) {
        float4 av = make_float4(0.f, 0.f, 0.f, 0.f);
        int arow = m0 + ar;
        if (arow < M) av = *(const float4*)(A + (size_t)arow * 256 + k0 + ak);
        As[ak + 0][ar] = av.x; As[ak + 1][ar] = av.y;
        As[ak + 2][ar] = av.z; As[ak + 3][ar] = av.w;
        float4 bv = *(const float4*)(B + (size_t)(k0 + bk) * 256 + n0 + bn);
        *(float4*)&Bs[bk][bn] = bv;
        __syncthreads();
#pragma unroll
        for (int kk = 0; kk < 16; kk++) {
            float4 a = *(const float4*)&As[kk][ty << 2];
            float4 b = *(const float4*)&Bs[kk][tx << 2];
            acc[0][0] += a.x * b.x; acc[0][1] += a.x * b.y; acc[0][2] += a.x * b.z; acc[0][3] += a.x * b.w;
            acc[1][0] += a.y * b.x; acc[1][1] += a.y * b.y; acc[1][2] += a.y * b.z; acc[1][3] += a.y * b.w;
            acc[2][0] += a.z * b.x; acc[2][1] += a.z * b.y; acc[2][2] += a.z * b.z; acc[2][3] += a.z * b.w;
            acc[3][0] += a.w * b.x; acc[3][1] += a.w * b.y; acc[3][2] += a.w * b.z; acc[3][3] += a.w * b.w;
        }
        __syncthreads();
    }
#pragma unroll
    for (int i = 0; i < 4; i++) {
        int row = m0 + (ty << 2) + i;
        if (row < M) {
            size_t o = (size_t)row * 256 + n0 + (tx << 2);
            float4 v = make_float4(acc[i][0], acc[i][1], acc[i][2], acc[i][3]);
            *(float4*)(C + o) = v;
            float dv = dinv[row];
            ushort4 vb;
            vb.x = f2bf(v.x * dv); vb.y = f2bf(v.y * dv);
            vb.z = f2bf(v.z * dv); vb.w = f2bf(v.w * dv);
            *(ushort4*)(Cb + o) = vb;
        }
    }
}

// ---------------------------------------------------------------- plain gemm kernel (layer 2)
__global__ __launch_bounds__(256) void gemm_kernel(const float* __restrict__ A,
                                                   const float* __restrict__ B,
                                                   const float* __restrict__ dinv,
                                                   float* __restrict__ C,
                                                   unsigned short* __restrict__ Cb,
                                                   int M) {
    gemm_body(A, B, dinv, C, Cb, M, blockIdx.x, blockIdx.y);
}

// ---------------------------------------------------------------- fused fill + gemm1
__global__ __launch_bounds__(256) void fill_gemm_kernel(const int* __restrict__ src,
                                                        const int* __restrict__ dst,
                                                        int* __restrict__ cursor,
                                                        unsigned short* __restrict__ csr_srcu,
                                                        const float* __restrict__ A,
                                                        const float* __restrict__ B,
                                                        const float* __restrict__ dinv,
                                                        float* __restrict__ C,
                                                        unsigned short* __restrict__ Cb) {
    if (blockIdx.x < GEMM_BLK) {
        gemm_body(A, B, dinv, C, Cb, NP, blockIdx.x >> 2, blockIdx.x & 3);
        return;
    }
    int e = (blockIdx.x - GEMM_BLK) * 256 + threadIdx.x;
    if (e >= ESG) return;
    int s = src[e], d = dst[e];
    int pos = atomicAdd(&cursor[d], 1);
    csr_srcu[pos] = (unsigned short)s;
}

// ---------------------------------------------------------------- SpMM, XCD-sliced + LDS-staged burst
// grid = NP blocks (4 waves): block = 4 rows x ONE 64-ch slice (slice=blockIdx&3,
// quad=blockIdx>>2); XCD k touches only slice k%4 -> 2.43 MB per-XCD gather set,
// L2-resident (round-9 verified: FETCH 36 MB).
// Per wave: stage 64 edge byte-offsets into wave-private LDS (one coalesced
// 128 B load, no barrier needed: same-wave ds_write->ds_read is ordered), then
// a fully-unrolled 16x4-edge gather burst (4 edge-groups x 16 lanes x ushort4)
// -> 16 independent 512 B gathers in flight instead of one dependent chain.
__global__ __launch_bounds__(256) void spmm_kernel(const unsigned short* __restrict__ hwbf,
                                                   const float* __restrict__ hw,
                                                   const int* __restrict__ row_ptr,
                                                   const unsigned short* __restrict__ csr_srcu,
                                                   const float* __restrict__ dinv,
                                                   const float* __restrict__ bias,
                                                   const float* __restrict__ residual,
                                                   float* __restrict__ outf,
                                                   unsigned short* __restrict__ outbf,
                                                   int do_relu) {
    int b     = blockIdx.x;
    int slice = b & 3;
    int quad  = b >> 2;                        // 0 .. NP/4-1
    int wv    = threadIdx.x >> 6;
    int lane  = threadIdx.x & 63;
    int g     = lane >> 4;                     // edge group 0..3
    int l     = lane & 15;                     // channel quad within slice
    int row   = quad * 4 + wv;                 // < NP
    int c     = slice * 64 + (l << 2);
    __shared__ int s_off[4][64];               // wave-private byte offsets
    int lo = __builtin_amdgcn_readfirstlane(row_ptr[row]);
    int hi = __builtin_amdgcn_readfirstlane(row_ptr[row + 1]);
    float a0 = 0.f, a1 = 0.f, a2 = 0.f, a3 = 0.f;
    const char* hp = (const char*)(hwbf + c);
    int nfull = (hi - lo) & ~63;
    for (int base = lo; base < lo + nfull; base += 64) {
        s_off[wv][lane] = (int)csr_srcu[base + lane] << 9;   // *256 ch *2 B
#pragma unroll
        for (int j = 0; j < 64; j += 4) {
            int off = s_off[wv][j + g];
            ushort4 hv = *(const ushort4*)(hp + off);
            a0 += bf2f(hv.x); a1 += bf2f(hv.y);
            a2 += bf2f(hv.z); a3 += bf2f(hv.w);
        }
    }
    int tb  = lo + nfull;
    int rem = hi - tb;
    if (rem) {
        if (lane < rem) s_off[wv][lane] = (int)csr_srcu[tb + lane] << 9;
        int fr = rem & ~3;
#pragma unroll 4
        for (int j = 0; j < fr; j += 4) {
            int off = s_off[wv][j + g];
            ushort4 hv = *(const ushort4*)(hp + off);
            a0 += bf2f(hv.x); a1 += bf2f(hv.y);
            a2 += bf2f(hv.z); a3 += bf2f(hv.w);
        }
        if (g < rem - fr) {
            int off = s_off[wv][fr + g];
            ushort4 hv = *(const ushort4*)(hp + off);
            a0 += bf2f(hv.x); a1 += bf2f(hv.y);
            a2 += bf2f(hv.z); a3 += bf2f(hv.w);
        }
    }
    // combine the 4 edge-groups (same channels, different edges)
    a0 += __shfl_xor(a0, 16); a1 += __shfl_xor(a1, 16);
    a2 += __shfl_xor(a2, 16); a3 += __shfl_xor(a3, 16);
    a0 += __shfl_xor(a0, 32); a1 += __shfl_xor(a1, 32);
    a2 += __shfl_xor(a2, 32); a3 += __shfl_xor(a3, 32);
    if (g == 0) {
        float dvr = dinv[row];
        float sn  = dvr * dvr;
        size_t o = (size_t)row * 256 + c;
        float4 hv = *(const float4*)(hw + o);
        float4 bv = *(const float4*)(bias + c);
        a0 = a0 * dvr + hv.x * sn + bv.x;
        a1 = a1 * dvr + hv.y * sn + bv.y;
        a2 = a2 * dvr + hv.z * sn + bv.z;
        a3 = a3 * dvr + hv.w * sn + bv.w;
        if (residual) {
            float4 rv = *(const float4*)(residual + o);
            a0 += rv.x; a1 += rv.y; a2 += rv.z; a3 += rv.w;
        }
        if (do_relu) {
            a0 = fmaxf(a0, 0.f); a1 = fmaxf(a1, 0.f);
            a2 = fmaxf(a2, 0.f); a3 = fmaxf(a3, 0.f);
        }
        if (outf)  *(float4*)(outf + o) = make_float4(a0, a1, a2, a3);
        if (outbf) {
            ushort4 ob; ob.x = f2bf(a0); ob.y = f2bf(a1); ob.z = f2bf(a2); ob.w = f2bf(a3);
            *(ushort4*)(outbf + o) = ob;
        }
    }
}

// ---------------------------------------------------------------- pooling, XCD-sliced + LDS-staged burst
// grid = ND*4; slice = blockIdx&3, drug = blockIdx>>2. 4 waves = 4 quarters of
// the node list; per wave: stage 64 node offsets in LDS, unrolled 4-node bursts.
__global__ __launch_bounds__(256) void pool_kernel(const unsigned short* __restrict__ h2bf,
                                                   const int* __restrict__ sg_nodes,
                                                   const int* __restrict__ sg_idx,
                                                   float* __restrict__ drug_emb) {
    int b     = blockIdx.x;
    int slice = b & 3;
    int d     = b >> 2;                        // < ND
    int wv    = threadIdx.x >> 6;
    int lane  = threadIdx.x & 63;
    int g     = lane >> 4;
    int l     = lane & 15;
    int c     = slice * 64 + (l << 2);
    __shared__ int   s_off[4][64];
    __shared__ float s_red[4][64];
    int lo0 = lower_bound_dev(sg_idx, NSG, d);       // uniform across block
    int hi0 = lower_bound_dev(sg_idx, NSG, d + 1);
    int len = hi0 - lo0;
    int lo = __builtin_amdgcn_readfirstlane(lo0 + (int)(((long long)len * wv) / 4));
    int hi = __builtin_amdgcn_readfirstlane(lo0 + (int)(((long long)len * (wv + 1)) / 4));
    float a0 = 0.f, a1 = 0.f, a2 = 0.f, a3 = 0.f;
    const char* hp = (const char*)(h2bf + c);
    int nfull = (hi - lo) & ~63;
    for (int base = lo; base < lo + nfull; base += 64) {
        s_off[wv][lane] = sg_nodes[base + lane] << 9;
#pragma unroll
        for (int j = 0; j < 64; j += 4) {
            int off = s_off[wv][j + g];
            ushort4 hv = *(const ushort4*)(hp + off);
            a0 += bf2f(hv.x); a1 += bf2f(hv.y);
            a2 += bf2f(hv.z); a3 += bf2f(hv.w);
        }
    }
    int tb  = lo + nfull;
    int rem = hi - tb;
    if (rem) {
        if (lane < rem) s_off[wv][lane] = sg_nodes[tb + lane] << 9;
        int fr = rem & ~3;
#pragma unroll 4
        for (int j = 0; j < fr; j += 4) {
            int off = s_off[wv][j + g];
            ushort4 hv = *(const ushort4*)(hp + off);
            a0 += bf2f(hv.x); a1 += bf2f(hv.y);
            a2 += bf2f(hv.z); a3 += bf2f(hv.w);
        }
        if (g < rem - fr) {
            int off = s_off[wv][fr + g];
            ushort4 hv = *(const ushort4*)(hp + off);
            a0 += bf2f(hv.x); a1 += bf2f(hv.y);
            a2 += bf2f(hv.z); a3 += bf2f(hv.w);
        }
    }
    a0 += __shfl_xor(a0, 16); a1 += __shfl_xor(a1, 16);
    a2 += __shfl_xor(a2, 16); a3 += __shfl_xor(a3, 16);
    a0 += __shfl_xor(a0, 32); a1 += __shfl_xor(a1, 32);
    a2 += __shfl_xor(a2, 32); a3 += __shfl_xor(a3, 32);
    if (g == 0) *(float4*)&s_red[wv][l << 2] = make_float4(a0, a1, a2, a3);
    __syncthreads();
    if (threadIdx.x < 64) {
        int t = threadIdx.x;
        float inv = 1.0f / (float)max(len, 1);
        float r = (s_red[0][t] + s_red[1][t]) + (s_red[2][t] + s_red[3][t]);
        drug_emb[(size_t)d * 256 + slice * 64 + t] = r * inv;
    }
}

// ---------------------------------------------------------------- dot head (wave per pair)
__global__ __launch_bounds__(256) void dot_kernel(const float* __restrict__ drug_emb,
                                                  const int* __restrict__ ddb,
                                                  float* __restrict__ out) {
    int wave = threadIdx.x >> 6;
    int lane = threadIdx.x & 63;
    int p = blockIdx.x * 4 + wave;
    if (p >= BDD) return;
    int a = ddb[p];
    int b = ddb[BDD + p];
    const float4* ea = (const float4*)(drug_emb + (size_t)a * 256);
    const float4* eb = (const float4*)(drug_emb + (size_t)b * 256);
    float4 va = ea[lane];
    float4 vb = eb[lane];
    float s = va.x * vb.x + va.y * vb.y + va.z * vb.z + va.w * vb.w;
#pragma unroll
    for (int off = 32; off > 0; off >>= 1) s += __shfl_down(s, off, 64);
    if (lane == 0) out[p] = s;
}

// ---------------------------------------------------------------- launcher
extern "C" void kernel_launch(void* const* d_in, const int* in_sizes, int n_in,
                              void* d_out, int out_size, void* d_ws, size_t ws_size,
                              hipStream_t stream) {
    const float* x        = (const float*)d_in[0];
    const int*   ddb      = (const int*)d_in[1];
    // d_in[2] edge_attr, d_in[3] edge_cell_lines: unused by reference
    const int*   sg_edge  = (const int*)d_in[4];   // [2, ESG]: src then dst
    const int*   sg_nodes = (const int*)d_in[5];
    const int*   sg_idx   = (const int*)d_in[6];
    const float* W1       = (const float*)d_in[7];
    const float* b1       = (const float*)d_in[8];
    const float* W2       = (const float*)d_in[9];
    const float* b2       = (const float*)d_in[10];
    float* out = (float*)d_out;

    char* ws = (char*)d_ws;
    size_t off = 0;
    auto alloc = [&](size_t bytes) -> void* {
        void* p = ws + off;
        off = (off + bytes + 255) & ~(size_t)255;
        return p;
    };
    int*   deg      = (int*)alloc(NP * sizeof(int));
    float* dinv     = (float*)alloc(NP * sizeof(float));
    int*   row_ptr  = (int*)alloc((NP + 1) * sizeof(int));
    int*   cursor   = (int*)alloc(NP * sizeof(int));
    unsigned short* csr_srcu = (unsigned short*)alloc((size_t)ESG * sizeof(unsigned short));
    float* bufA     = (float*)alloc((size_t)NP * CHN * sizeof(float));            // hw1, then hw2
    unsigned short* bufAbf = (unsigned short*)alloc((size_t)NP * CHN * 2);        // bf16 twin (prescaled)
    float* h1       = (float*)alloc((size_t)NP * CHN * sizeof(float));
    unsigned short* h2bf   = (unsigned short*)alloc((size_t)NP * CHN * 2);
    float* drug_emb = (float*)alloc((size_t)ND * CHN * sizeof(float));

    const int* src = sg_edge;
    const int* dst = sg_edge + ESG;

    hipMemsetAsync(deg, 0, NP * sizeof(int), stream);
    deg_kernel<<<(ESG + 255) / 256, 256, 0, stream>>>(dst, deg);
    scan_kernel<<<1, 256, 0, stream>>>(deg, row_ptr, cursor, dinv);

    // fused: CSR fill (ushort src) + gemm1 (bufA fp32; bufAbf bf16 prescaled)
    fill_gemm_kernel<<<GEMM_BLK + FILL_BLK, 256, 0, stream>>>(src, dst, cursor,
                                                              csr_srcu, x, W1, dinv,
                                                              bufA, bufAbf);
    // layer 1: h1 = relu(agg(sliced gather) + self + b1)   [fp32 out only]
    spmm_kernel<<<NP, 256, 0, stream>>>(bufAbf, bufA, row_ptr, csr_srcu, dinv, b1,
                                        nullptr, h1, nullptr, 1);
    // layer 2: bufA/bufAbf = h1 @ W2 ; h2bf = agg + self + b2 + h1  [bf16 out only]
    gemm_kernel<<<dim3(GEMM_BX, 4), 256, 0, stream>>>(h1, W2, dinv, bufA, bufAbf, NP);
    spmm_kernel<<<NP, 256, 0, stream>>>(bufAbf, bufA, row_ptr, csr_srcu, dinv, b2,
                                        h1, nullptr, h2bf, 0);
    // scatter-mean pooling (XCD-sliced, LDS-staged)
    pool_kernel<<<ND * 4, 256, 0, stream>>>(h2bf, sg_nodes, sg_idx, drug_emb);
    // dot-product head
    dot_kernel<<<(BDD + 3) / 4, 256, 0, stream>>>(drug_emb, ddb, out);
}